// Round 1
// baseline (3184.267 us; speedup 1.0000x reference)
//
#include <hip/hip_runtime.h>
#include <hip/hip_bf16.h>
#include <math.h>

#define RREL 6
#define NN   50000
#define EE   200000
#define DD   768
#define HH   4
#define CC   64
#define HC   256
#define OO   64
#define MPAD 50048   // 391 * 128

typedef __attribute__((ext_vector_type(8))) short short8;
typedef __attribute__((ext_vector_type(4))) float f32x4;

// ---------- x -> bf16, zero-padded to MPAD rows ----------
__global__ void k_cvt_x(const float* __restrict__ x, __hip_bfloat16* __restrict__ xb) {
  int idx = blockIdx.x * blockDim.x + threadIdx.x;
  if (idx >= MPAD * DD) return;
  int row = idx / DD;
  float v = (row < NN) ? x[idx] : 0.f;
  xb[idx] = __float2bfloat16(v);
}

// ---------- repack Wl|Wr -> Wt[r][512][768] bf16 (N-major, i.e. B^T) ----------
__global__ void k_repack_w(const float* __restrict__ Wl, const float* __restrict__ Wr,
                           __hip_bfloat16* __restrict__ Wt) {
  int idx = blockIdx.x * blockDim.x + threadIdx.x;
  if (idx >= RREL * 512 * DD) return;
  int k = idx % DD;
  int j = (idx / DD) % 512;
  int r = idx / (512 * DD);
  float v = (j < HC) ? Wl[((size_t)r * DD + k) * HC + j]
                     : Wr[((size_t)r * DD + k) * HC + (j - HC)];
  Wt[idx] = __float2bfloat16(v);
}

// ---------- bf16 MFMA GEMM: Y[MPAD][512] = Xb[MPAD][768] @ Wt_r[512][768]^T ----------
__global__ __launch_bounds__(256) void k_gemm(const __hip_bfloat16* __restrict__ A,
                                              const __hip_bfloat16* __restrict__ Bt,
                                              float* __restrict__ Y) {
  __shared__ __align__(16) short As[128 * 32];
  __shared__ __align__(16) short Bs[128 * 32];
  int tid = threadIdx.x;
  int bm = blockIdx.x, bn = blockIdx.y;
  int lane = tid & 63, wave = tid >> 6;
  int wm = (wave & 1) * 64, wn = (wave >> 1) * 64;
  int quad = lane >> 4, l16 = lane & 15;
  f32x4 acc[4][4] = {};
  const short* Ag = (const short*)A + (long)(bm * 128) * DD;
  const short* Bg = (const short*)Bt + (long)(bn * 128) * DD;
  int r0 = tid >> 2, c0 = (tid & 3) * 8;
  for (int k0 = 0; k0 < DD; k0 += 32) {
    *(uint4*)&As[r0 * 32 + c0]        = *(const uint4*)&Ag[(long)r0 * DD + k0 + c0];
    *(uint4*)&As[(r0 + 64) * 32 + c0] = *(const uint4*)&Ag[(long)(r0 + 64) * DD + k0 + c0];
    *(uint4*)&Bs[r0 * 32 + c0]        = *(const uint4*)&Bg[(long)r0 * DD + k0 + c0];
    *(uint4*)&Bs[(r0 + 64) * 32 + c0] = *(const uint4*)&Bg[(long)(r0 + 64) * DD + k0 + c0];
    __syncthreads();
    short8 af[4], bf[4];
#pragma unroll
    for (int i = 0; i < 4; i++) af[i] = *(const short8*)&As[(wm + i * 16 + l16) * 32 + quad * 8];
#pragma unroll
    for (int j = 0; j < 4; j++) bf[j] = *(const short8*)&Bs[(wn + j * 16 + l16) * 32 + quad * 8];
#pragma unroll
    for (int i = 0; i < 4; i++)
#pragma unroll
      for (int j = 0; j < 4; j++)
        acc[i][j] = __builtin_amdgcn_mfma_f32_16x16x32_bf16(af[i], bf[j], acc[i][j], 0, 0, 0);
    __syncthreads();
  }
#pragma unroll
  for (int i = 0; i < 4; i++)
#pragma unroll
    for (int j = 0; j < 4; j++)
#pragma unroll
      for (int reg = 0; reg < 4; reg++) {
        int row = bm * 128 + wm + i * 16 + quad * 4 + reg;   // C/D: row = quad*4+reg
        int col = bn * 128 + wn + j * 16 + l16;              //      col = lane&15
        Y[(long)row * 512 + col] = acc[i][j][reg];
      }
}

// ---------- CSR build ----------
__global__ void k_deg(const int* __restrict__ tgt, int* __restrict__ deg) {
  int e = blockIdx.x * blockDim.x + threadIdx.x;
  if (e < EE) atomicAdd(&deg[tgt[e]], 1);
}

__global__ void k_scan(const int* __restrict__ deg, int* __restrict__ off,
                       int* __restrict__ cursor, int n) {
  __shared__ int wsum[16];
  __shared__ int s_carry;
  int tid = threadIdx.x, lane = tid & 63, wid = tid >> 6;
  if (tid == 0) s_carry = 0;
  __syncthreads();
  for (int base = 0; base < n; base += 1024) {
    int i = base + tid;
    int v = (i < n) ? deg[i] : 0;
    int incl = v;
#pragma unroll
    for (int d = 1; d < 64; d <<= 1) { int t = __shfl_up(incl, d); if (lane >= d) incl += t; }
    if (lane == 63) wsum[wid] = incl;
    __syncthreads();
    if (wid == 0) {
      int wv = (lane < 16) ? wsum[lane] : 0;
#pragma unroll
      for (int d = 1; d < 16; d <<= 1) { int t = __shfl_up(wv, d); if (lane >= d) wv += t; }
      if (lane < 16) wsum[lane] = wv;
    }
    __syncthreads();
    int pre = (wid > 0 ? wsum[wid - 1] : 0) + s_carry;
    int excl = pre + incl - v;
    if (i < n) { off[i] = excl; cursor[i] = excl; }
    __syncthreads();
    if (tid == 0) s_carry += wsum[15];
    __syncthreads();
  }
}

__global__ void k_scatter(const int* __restrict__ tgt, int* __restrict__ cursor,
                          int* __restrict__ eidx) {
  int e = blockIdx.x * blockDim.x + threadIdx.x;
  if (e < EE) { int p = atomicAdd(&cursor[tgt[e]], 1); eidx[p] = e; }
}

// ---------- fused GATv2: logits + exp + softmax-denom + weighted agg + bias + relu ----------
// one wave per target node; lane = c within each head
__global__ __launch_bounds__(256) void k_gat(const float* __restrict__ Y, const int* __restrict__ srcs,
                                             const int* __restrict__ off, const int* __restrict__ deg,
                                             const int* __restrict__ eidx,
                                             const float* __restrict__ att, const float* __restrict__ bg,
                                             float* __restrict__ h1) {
  int lane = threadIdx.x & 63;
  int n = blockIdx.x * 4 + (threadIdx.x >> 6);
  if (n >= NN) return;
  const float* yb = Y + (long)n * 512;
  float xr[HH], xlt[HH], at[HH];
#pragma unroll
  for (int h = 0; h < HH; h++) {
    xr[h]  = yb[HC + h * CC + lane];
    xlt[h] = yb[h * CC + lane];
    at[h]  = att[h * CC + lane];
  }
  float num[HH] = {0.f, 0.f, 0.f, 0.f}, den[HH] = {0.f, 0.f, 0.f, 0.f};
  int st = off[n], cnt = deg[n];
  for (int i = -1; i < cnt; i++) {   // i == -1 is the self loop
    float xv[HH], lg[HH];
    if (i < 0) {
#pragma unroll
      for (int h = 0; h < HH; h++) xv[h] = xlt[h];
    } else {
      int s = srcs[eidx[st + i]];
      const float* xs = Y + (long)s * 512;
#pragma unroll
      for (int h = 0; h < HH; h++) xv[h] = xs[h * CC + lane];
    }
#pragma unroll
    for (int h = 0; h < HH; h++) {
      float e = xv[h] + xr[h];
      e = e > 0.f ? e : 0.2f * e;     // leaky_relu 0.2
      lg[h] = at[h] * e;
    }
#pragma unroll
    for (int m = 1; m < 64; m <<= 1)
#pragma unroll
      for (int h = 0; h < HH; h++) lg[h] += __shfl_xor(lg[h], m);
#pragma unroll
    for (int h = 0; h < HH; h++) {
      float a = expf(lg[h]);          // no max-subtract needed: |logit| ~ O(1)
      den[h] += a;
      num[h] += a * xv[h];
    }
  }
#pragma unroll
  for (int h = 0; h < HH; h++)
    h1[(long)n * HC + h * CC + lane] =
        fmaxf(num[h] / (den[h] + 1e-16f) + bg[h * CC + lane], 0.f);
}

// ---------- CSR gather-sum of h1 (256 wide) ----------
__global__ __launch_bounds__(256) void k_agg1(const float* __restrict__ h1, const int* __restrict__ srcs,
                                              const int* __restrict__ off, const int* __restrict__ deg,
                                              const int* __restrict__ eidx, float* __restrict__ agg) {
  int lane = threadIdx.x & 63;
  int n = blockIdx.x * 4 + (threadIdx.x >> 6);
  if (n >= NN) return;
  float acc[4] = {0.f, 0.f, 0.f, 0.f};
  int st = off[n], cnt = deg[n];
  for (int i = 0; i < cnt; i++) {
    int s = srcs[eidx[st + i]];
    const float* hs = h1 + (long)s * HC;
#pragma unroll
    for (int j = 0; j < 4; j++) acc[j] += hs[j * CC + lane];
  }
#pragma unroll
  for (int j = 0; j < 4; j++) agg[(long)n * HC + j * CC + lane] = acc[j];
}

// ---------- GraphConv1: h2 = relu(agg1@Wrel + h1@Wroot + b) ----------
__global__ __launch_bounds__(256) void k_gc1(const float* __restrict__ agg, const float* __restrict__ h1,
                                             const float* __restrict__ Wrel, const float* __restrict__ Wroot,
                                             const float* __restrict__ b, float* __restrict__ h2) {
  __shared__ float sA[16][520];   // pad 8: rows p0={0..3} land on distinct banks
  int tid = threadIdx.x;
  int n0 = blockIdx.x * 16;
  for (int idx = tid; idx < 16 * 512; idx += 256) {
    int nl = idx >> 9, k = idx & 511;
    int n = n0 + nl;
    float v = 0.f;
    if (n < NN) v = (k < HC) ? agg[(long)n * HC + k] : h1[(long)n * HC + (k - HC)];
    sA[nl][k] = v;
  }
  __syncthreads();
  int o = tid & 63, p0 = tid >> 6;
  float acc[4] = {0.f, 0.f, 0.f, 0.f};
  for (int k = 0; k < HC; k++) {
    float wr = Wrel[k * OO + o];
    float wo = Wroot[k * OO + o];
#pragma unroll
    for (int p = 0; p < 4; p++) {
      int nl = p0 + p * 4;
      acc[p] += sA[nl][k] * wr + sA[nl][HC + k] * wo;
    }
  }
  float bb = b[o];
#pragma unroll
  for (int p = 0; p < 4; p++) {
    int n = n0 + p0 + p * 4;
    if (n < NN) h2[(long)n * OO + o] = fmaxf(acc[p] + bb, 0.f);
  }
}

// ---------- CSR gather-sum of h2 (64 wide) ----------
__global__ __launch_bounds__(256) void k_agg2(const float* __restrict__ h2, const int* __restrict__ srcs,
                                              const int* __restrict__ off, const int* __restrict__ deg,
                                              const int* __restrict__ eidx, float* __restrict__ agg2) {
  int lane = threadIdx.x & 63;
  int n = blockIdx.x * 4 + (threadIdx.x >> 6);
  if (n >= NN) return;
  float acc = 0.f;
  int st = off[n], cnt = deg[n];
  for (int i = 0; i < cnt; i++) {
    int s = srcs[eidx[st + i]];
    acc += h2[(long)s * OO + lane];
  }
  agg2[(long)n * OO + lane] = acc;
}

// ---------- GraphConv2 + write out[n][r][o] (no relu) ----------
__global__ __launch_bounds__(256) void k_gc2(const float* __restrict__ agg2, const float* __restrict__ h2,
                                             const float* __restrict__ Wrel, const float* __restrict__ Wroot,
                                             const float* __restrict__ b, float* __restrict__ out, int r) {
  __shared__ float sB[16][136];   // 128 + pad 8
  int tid = threadIdx.x;
  int n0 = blockIdx.x * 16;
  for (int idx = tid; idx < 16 * 128; idx += 256) {
    int nl = idx >> 7, k = idx & 127;
    int n = n0 + nl;
    float v = 0.f;
    if (n < NN) v = (k < OO) ? agg2[(long)n * OO + k] : h2[(long)n * OO + (k - OO)];
    sB[nl][k] = v;
  }
  __syncthreads();
  int o = tid & 63, p0 = tid >> 6;
  float acc[4] = {0.f, 0.f, 0.f, 0.f};
  for (int k = 0; k < OO; k++) {
    float wr = Wrel[k * OO + o];
    float wo = Wroot[k * OO + o];
#pragma unroll
    for (int p = 0; p < 4; p++) {
      int nl = p0 + p * 4;
      acc[p] += sB[nl][k] * wr + sB[nl][OO + k] * wo;
    }
  }
  float bb = b[o];
#pragma unroll
  for (int p = 0; p < 4; p++) {
    int n = n0 + p0 + p * 4;
    if (n < NN) out[(long)n * (RREL * OO) + r * OO + o] = acc[p] + bb;
  }
}

extern "C" void kernel_launch(void* const* d_in, const int* in_sizes, int n_in,
                              void* d_out, int out_size, void* d_ws, size_t ws_size,
                              hipStream_t stream) {
  (void)in_sizes; (void)n_in; (void)out_size;
  const float* x      = (const float*)d_in[0];
  const int*   ei     = (const int*)d_in[1];
  const float* Wl     = (const float*)d_in[2];
  const float* Wr     = (const float*)d_in[3];
  const float* att    = (const float*)d_in[4];
  const float* bg     = (const float*)d_in[5];
  const float* Wrel1  = (const float*)d_in[6];
  const float* Wroot1 = (const float*)d_in[7];
  const float* b1     = (const float*)d_in[8];
  const float* Wrel2  = (const float*)d_in[9];
  const float* Wroot2 = (const float*)d_in[10];
  const float* b2     = (const float*)d_in[11];
  float* out = (float*)d_out;

  char* ws = (char*)d_ws;
  size_t ofs = 0;
  auto alloc = [&](size_t bytes) {
    char* p = ws + ofs;
    ofs += (bytes + 255) & ~(size_t)255;
    return p;
  };
  __hip_bfloat16* Xb = (__hip_bfloat16*)alloc((size_t)MPAD * DD * 2);
  __hip_bfloat16* Wt = (__hip_bfloat16*)alloc((size_t)RREL * 512 * DD * 2);
  float* Y    = (float*)alloc((size_t)MPAD * 512 * 4);
  int* deg    = (int*)alloc((size_t)NN * 4);
  int* off_   = (int*)alloc((size_t)NN * 4);
  int* cursor = (int*)alloc((size_t)NN * 4);
  int* eidx   = (int*)alloc((size_t)EE * 4);
  float* h1   = (float*)alloc((size_t)NN * HC * 4);
  float* agg1 = (float*)alloc((size_t)NN * HC * 4);
  float* h2   = (float*)alloc((size_t)NN * OO * 4);
  float* agg2 = (float*)alloc((size_t)NN * OO * 4);
  if (ofs > ws_size) return;  // workspace too small — fail visibly

  k_cvt_x<<<(MPAD * DD + 255) / 256, 256, 0, stream>>>(x, Xb);
  k_repack_w<<<(RREL * 512 * DD + 255) / 256, 256, 0, stream>>>(Wl, Wr, Wt);

  for (int r = 0; r < RREL; r++) {
    const int* srcs = ei + (size_t)r * 2 * EE;
    const int* tgts = srcs + EE;
    k_gemm<<<dim3(MPAD / 128, 4), 256, 0, stream>>>(Xb, Wt + (size_t)r * 512 * DD, Y);
    hipMemsetAsync(deg, 0, (size_t)NN * 4, stream);
    k_deg<<<(EE + 255) / 256, 256, 0, stream>>>(tgts, deg);
    k_scan<<<1, 1024, 0, stream>>>(deg, off_, cursor, NN);
    k_scatter<<<(EE + 255) / 256, 256, 0, stream>>>(tgts, cursor, eidx);
    k_gat<<<NN / 4, 256, 0, stream>>>(Y, srcs, off_, deg, eidx, att + r * HC, bg + r * HC, h1);
    k_agg1<<<NN / 4, 256, 0, stream>>>(h1, srcs, off_, deg, eidx, agg1);
    k_gc1<<<(NN + 15) / 16, 256, 0, stream>>>(agg1, h1, Wrel1 + (size_t)r * HC * OO,
                                              Wroot1 + (size_t)r * HC * OO, b1 + r * OO, h2);
    k_agg2<<<NN / 4, 256, 0, stream>>>(h2, srcs, off_, deg, eidx, agg2);
    k_gc2<<<(NN + 15) / 16, 256, 0, stream>>>(agg2, h2, Wrel2 + (size_t)r * OO * OO,
                                              Wroot2 + (size_t)r * OO * OO, b2 + r * OO, out, r);
  }
}

// Round 2
// 2049.597 us; speedup vs baseline: 1.5536x; 1.5536x over previous
//
#include <hip/hip_runtime.h>
#include <hip/hip_bf16.h>
#include <math.h>

#define RREL 6
#define NN   50000
#define EE   200000
#define DD   768
#define HH   4
#define CC   64
#define HC   256
#define OO   64
#define MPAD 50048   // 391 * 128

typedef __attribute__((ext_vector_type(8))) short short8;
typedef __attribute__((ext_vector_type(4))) float f32x4;

// CK-style addrspace cast through integer for global_load_lds (16B per lane;
// LDS dest is wave-uniform base + lane*16)
__device__ __forceinline__ void gload16(const void* g, void* s) {
  typedef __attribute__((address_space(1))) void gvoid;
  typedef __attribute__((address_space(3))) void svoid;
  __builtin_amdgcn_global_load_lds((gvoid*)(unsigned long long)g,
                                   (svoid*)(unsigned long long)s, 16, 0, 0);
}

// ---------- x -> bf16, zero-padded to MPAD rows ----------
__global__ void k_cvt_x(const float* __restrict__ x, __hip_bfloat16* __restrict__ xb) {
  int idx = blockIdx.x * blockDim.x + threadIdx.x;
  if (idx >= MPAD * DD) return;
  int row = idx / DD;
  float v = (row < NN) ? x[idx] : 0.f;
  xb[idx] = __float2bfloat16(v);
}

// ---------- repack Wl|Wr -> Wt[r][512][768] bf16 (N-major, B^T) ----------
__global__ void k_repack_w(const float* __restrict__ Wl, const float* __restrict__ Wr,
                           __hip_bfloat16* __restrict__ Wt) {
  int idx = blockIdx.x * blockDim.x + threadIdx.x;
  if (idx >= RREL * 512 * DD) return;
  int k = idx % DD;
  int j = (idx / DD) % 512;
  int r = idx / (512 * DD);
  float v = (j < HC) ? Wl[((size_t)r * DD + k) * HC + j]
                     : Wr[((size_t)r * DD + k) * HC + (j - HC)];
  Wt[idx] = __float2bfloat16(v);
}

// ---------- repack [Wrel;Wroot] -> Bt[r][64][K] bf16 ----------
__global__ void k_repack_gc(const float* __restrict__ Wrel, const float* __restrict__ Wroot,
                            __hip_bfloat16* __restrict__ Bt, int K) {
  int idx = blockIdx.x * blockDim.x + threadIdx.x;
  if (idx >= RREL * 64 * K) return;
  int k = idx % K;
  int o = (idx / K) % 64;
  int r = idx / (64 * K);
  int h = K >> 1;
  float v = (k < h) ? Wrel[((long)r * h + k) * 64 + o]
                    : Wroot[((long)r * h + (k - h)) * 64 + o];
  Bt[idx] = __float2bfloat16(v);
}

// ---------- big bf16 MFMA GEMM: Y[MPAD][512] = Xb @ Wt_r^T  (m97 structure) ----------
__global__ __launch_bounds__(256) void k_gemm(const short* __restrict__ A,
                                              const short* __restrict__ Bt,
                                              float* __restrict__ Y) {
  __shared__ __align__(16) short As[128 * 32];
  __shared__ __align__(16) short Bs[128 * 32];
  int tid = threadIdx.x;
  int bm = blockIdx.x, bn = blockIdx.y;
  int lane = tid & 63, wave = tid >> 6;
  int wm = (wave & 1) * 64, wn = (wave >> 1) * 64;
  int quad = lane >> 4, l16 = lane & 15;
  f32x4 acc[4][4] = {};
  const short* Ag = A + (long)bm * 128 * DD;
  const short* Bg = Bt + (long)bn * 128 * DD;
  int lr = lane >> 2, lc = (lane & 3) * 8;
  const short* ga0 = Ag + (long)(wave * 16 + lr) * DD + lc;
  const short* ga1 = Ag + (long)(64 + wave * 16 + lr) * DD + lc;
  const short* gb0 = Bg + (long)(wave * 16 + lr) * DD + lc;
  const short* gb1 = Bg + (long)(64 + wave * 16 + lr) * DD + lc;
  short* la0 = &As[(wave * 16) * 32];
  short* la1 = &As[(64 + wave * 16) * 32];
  short* lb0 = &Bs[(wave * 16) * 32];
  short* lb1 = &Bs[(64 + wave * 16) * 32];
  for (int k0 = 0; k0 < DD; k0 += 32) {
    gload16(ga0 + k0, la0);
    gload16(ga1 + k0, la1);
    gload16(gb0 + k0, lb0);
    gload16(gb1 + k0, lb1);
    __syncthreads();
    short8 af[4], bf[4];
#pragma unroll
    for (int i = 0; i < 4; i++) af[i] = *(const short8*)&As[(wm + i * 16 + l16) * 32 + quad * 8];
#pragma unroll
    for (int j = 0; j < 4; j++) bf[j] = *(const short8*)&Bs[(wn + j * 16 + l16) * 32 + quad * 8];
#pragma unroll
    for (int i = 0; i < 4; i++)
#pragma unroll
      for (int j = 0; j < 4; j++)
        acc[i][j] = __builtin_amdgcn_mfma_f32_16x16x32_bf16(af[i], bf[j], acc[i][j], 0, 0, 0);
    __syncthreads();
  }
#pragma unroll
  for (int i = 0; i < 4; i++)
#pragma unroll
    for (int j = 0; j < 4; j++)
#pragma unroll
      for (int reg = 0; reg < 4; reg++) {
        int row = bm * 128 + wm + i * 16 + quad * 4 + reg;
        int col = bn * 128 + wn + j * 16 + l16;
        Y[(long)row * 512 + col] = acc[i][j][reg];
      }
}

// ---------- small-N MFMA GEMM for GraphConv: out = A[MPAD][K] @ Bt[64][K]^T ----------
template <int K, bool RELU, bool OBF16>
__global__ __launch_bounds__(256) void k_gcgemm(const short* __restrict__ A,
                                                const short* __restrict__ Bt,
                                                const float* __restrict__ bias,
                                                void* __restrict__ outp, long ldo, int ocol) {
  __shared__ __align__(16) short As[128 * 32];
  __shared__ __align__(16) short Bs[64 * 32];
  int tid = threadIdx.x;
  int bm = blockIdx.x;
  int lane = tid & 63, wave = tid >> 6;
  int quad = lane >> 4, l16 = lane & 15;
  f32x4 acc[2][4] = {};
  const short* Ag = A + (long)bm * 128 * K;
  int lr = lane >> 2, lc = (lane & 3) * 8;
  const short* ga0 = Ag + (long)(wave * 16 + lr) * K + lc;
  const short* ga1 = Ag + (long)(64 + wave * 16 + lr) * K + lc;
  const short* gb0 = Bt + (long)(wave * 16 + lr) * K + lc;
  short* la0 = &As[(wave * 16) * 32];
  short* la1 = &As[(64 + wave * 16) * 32];
  short* lb0 = &Bs[(wave * 16) * 32];
  for (int k0 = 0; k0 < K; k0 += 32) {
    gload16(ga0 + k0, la0);
    gload16(ga1 + k0, la1);
    gload16(gb0 + k0, lb0);
    __syncthreads();
    short8 af[2], bf[4];
#pragma unroll
    for (int i = 0; i < 2; i++) af[i] = *(const short8*)&As[(wave * 32 + i * 16 + l16) * 32 + quad * 8];
#pragma unroll
    for (int j = 0; j < 4; j++) bf[j] = *(const short8*)&Bs[(j * 16 + l16) * 32 + quad * 8];
#pragma unroll
    for (int i = 0; i < 2; i++)
#pragma unroll
      for (int j = 0; j < 4; j++)
        acc[i][j] = __builtin_amdgcn_mfma_f32_16x16x32_bf16(af[i], bf[j], acc[i][j], 0, 0, 0);
    __syncthreads();
  }
#pragma unroll
  for (int i = 0; i < 2; i++)
#pragma unroll
    for (int j = 0; j < 4; j++)
#pragma unroll
      for (int reg = 0; reg < 4; reg++) {
        int row = bm * 128 + wave * 32 + i * 16 + quad * 4 + reg;
        int col = j * 16 + l16;
        float v = acc[i][j][reg] + bias[col];
        if (RELU) v = fmaxf(v, 0.f);
        if (OBF16) {
          ((__hip_bfloat16*)outp)[(long)row * ldo + ocol + col] = __float2bfloat16(v);
        } else {
          if (row < NN) ((float*)outp)[(long)row * ldo + ocol + col] = v;
        }
      }
}

// ---------- batched CSR build ----------
__global__ void k_deg6(const int* __restrict__ ei, int* __restrict__ deg6) {
  long e = (long)blockIdx.x * blockDim.x + threadIdx.x;
  if (e >= (long)RREL * EE) return;
  int r = e / EE, i = e % EE;
  int t = ei[(long)r * 2 * EE + EE + i];
  atomicAdd(&deg6[(long)r * NN + t], 1);
}

__global__ void k_scan6(const int* __restrict__ deg6, int* __restrict__ off6,
                        int* __restrict__ cur6) {
  int r = blockIdx.x;
  const int* deg = deg6 + (long)r * NN;
  int* off = off6 + (long)r * NN;
  int* cur = cur6 + (long)r * NN;
  __shared__ int wsum[16];
  __shared__ int s_carry;
  int tid = threadIdx.x, lane = tid & 63, wid = tid >> 6;
  if (tid == 0) s_carry = 0;
  __syncthreads();
  for (int base = 0; base < NN; base += 1024) {
    int i = base + tid;
    int v = (i < NN) ? deg[i] : 0;
    int incl = v;
#pragma unroll
    for (int d = 1; d < 64; d <<= 1) { int t = __shfl_up(incl, d); if (lane >= d) incl += t; }
    if (lane == 63) wsum[wid] = incl;
    __syncthreads();
    if (wid == 0) {
      int wv = (lane < 16) ? wsum[lane] : 0;
#pragma unroll
      for (int d = 1; d < 16; d <<= 1) { int t = __shfl_up(wv, d); if (lane >= d) wv += t; }
      if (lane < 16) wsum[lane] = wv;
    }
    __syncthreads();
    int pre = (wid > 0 ? wsum[wid - 1] : 0) + s_carry;
    int excl = pre + incl - v;
    if (i < NN) { off[i] = excl; cur[i] = excl; }
    __syncthreads();
    if (tid == 0) s_carry += wsum[15];
    __syncthreads();
  }
}

__global__ void k_scatter6(const int* __restrict__ ei, int* __restrict__ cur6,
                           int* __restrict__ eidx6) {
  long e = (long)blockIdx.x * blockDim.x + threadIdx.x;
  if (e >= (long)RREL * EE) return;
  int r = e / EE, i = e % EE;
  int t = ei[(long)r * 2 * EE + EE + i];
  int p = atomicAdd(&cur6[(long)r * NN + t], 1);
  eidx6[(long)r * EE + p] = i;
}

// ---------- fused GATv2 (wave per target node), h1 -> bf16 into AB1[:,256:512] ----------
__global__ __launch_bounds__(256) void k_gat(const float* __restrict__ Y, const int* __restrict__ srcs,
                                             const int* __restrict__ off, const int* __restrict__ deg,
                                             const int* __restrict__ eidx,
                                             const float* __restrict__ att, const float* __restrict__ bg,
                                             __hip_bfloat16* __restrict__ AB1) {
  int lane = threadIdx.x & 63;
  int n = blockIdx.x * 4 + (threadIdx.x >> 6);
  if (n >= NN) return;
  const float* yb = Y + (long)n * 512;
  float xr[HH], xlt[HH], at[HH];
#pragma unroll
  for (int h = 0; h < HH; h++) {
    xr[h]  = yb[HC + h * CC + lane];
    xlt[h] = yb[h * CC + lane];
    at[h]  = att[h * CC + lane];
  }
  float num[HH] = {0.f, 0.f, 0.f, 0.f}, den[HH] = {0.f, 0.f, 0.f, 0.f};
  int st = off[n], cnt = deg[n];
  for (int i = -1; i < cnt; i++) {   // i == -1 is the self loop
    float xv[HH], lg[HH];
    if (i < 0) {
#pragma unroll
      for (int h = 0; h < HH; h++) xv[h] = xlt[h];
    } else {
      int s = srcs[eidx[st + i]];
      const float* xs = Y + (long)s * 512;
#pragma unroll
      for (int h = 0; h < HH; h++) xv[h] = xs[h * CC + lane];
    }
#pragma unroll
    for (int h = 0; h < HH; h++) {
      float e = xv[h] + xr[h];
      e = e > 0.f ? e : 0.2f * e;
      lg[h] = at[h] * e;
    }
#pragma unroll
    for (int m = 1; m < 64; m <<= 1)
#pragma unroll
      for (int h = 0; h < HH; h++) lg[h] += __shfl_xor(lg[h], m);
#pragma unroll
    for (int h = 0; h < HH; h++) {
      float a = expf(lg[h]);
      den[h] += a;
      num[h] += a * xv[h];
    }
  }
#pragma unroll
  for (int h = 0; h < HH; h++) {
    float v = fmaxf(num[h] / (den[h] + 1e-16f) + bg[h * CC + lane], 0.f);
    AB1[(long)n * 512 + HC + h * CC + lane] = __float2bfloat16(v);
  }
}

// ---------- CSR gather-sum of h1(bf16) -> agg into AB1[:,0:256] ----------
__global__ __launch_bounds__(256) void k_agg1(__hip_bfloat16* __restrict__ AB1, const int* __restrict__ srcs,
                                              const int* __restrict__ off, const int* __restrict__ deg,
                                              const int* __restrict__ eidx) {
  int lane = threadIdx.x & 63;
  int n = blockIdx.x * 4 + (threadIdx.x >> 6);
  if (n >= NN) return;
  float acc[4] = {0.f, 0.f, 0.f, 0.f};
  int st = off[n], cnt = deg[n];
  for (int i = 0; i < cnt; i++) {
    int s = srcs[eidx[st + i]];
    const __hip_bfloat16* hs = AB1 + (long)s * 512 + HC;
#pragma unroll
    for (int j = 0; j < 4; j++) acc[j] += __bfloat162float(hs[j * CC + lane]);
  }
#pragma unroll
  for (int j = 0; j < 4; j++) AB1[(long)n * 512 + j * CC + lane] = __float2bfloat16(acc[j]);
}

// ---------- CSR gather-sum of h2(bf16) -> agg2 into AB2[:,0:64] ----------
__global__ __launch_bounds__(256) void k_agg2(__hip_bfloat16* __restrict__ AB2, const int* __restrict__ srcs,
                                              const int* __restrict__ off, const int* __restrict__ deg,
                                              const int* __restrict__ eidx) {
  int lane = threadIdx.x & 63;
  int n = blockIdx.x * 4 + (threadIdx.x >> 6);
  if (n >= NN) return;
  float acc = 0.f;
  int st = off[n], cnt = deg[n];
  for (int i = 0; i < cnt; i++) {
    int s = srcs[eidx[st + i]];
    acc += __bfloat162float(AB2[(long)s * 128 + OO + lane]);
  }
  AB2[(long)n * 128 + lane] = __float2bfloat16(acc);
}

extern "C" void kernel_launch(void* const* d_in, const int* in_sizes, int n_in,
                              void* d_out, int out_size, void* d_ws, size_t ws_size,
                              hipStream_t stream) {
  (void)in_sizes; (void)n_in; (void)out_size;
  const float* x      = (const float*)d_in[0];
  const int*   ei     = (const int*)d_in[1];
  const float* Wl     = (const float*)d_in[2];
  const float* Wr     = (const float*)d_in[3];
  const float* att    = (const float*)d_in[4];
  const float* bg     = (const float*)d_in[5];
  const float* Wrel1  = (const float*)d_in[6];
  const float* Wroot1 = (const float*)d_in[7];
  const float* b1     = (const float*)d_in[8];
  const float* Wrel2  = (const float*)d_in[9];
  const float* Wroot2 = (const float*)d_in[10];
  const float* b2     = (const float*)d_in[11];
  float* out = (float*)d_out;

  char* ws = (char*)d_ws;
  size_t ofs = 0;
  auto alloc = [&](size_t bytes) {
    char* p = ws + ofs;
    ofs += (bytes + 255) & ~(size_t)255;
    return p;
  };
  __hip_bfloat16* Xb  = (__hip_bfloat16*)alloc((size_t)MPAD * DD * 2);
  __hip_bfloat16* Wt  = (__hip_bfloat16*)alloc((size_t)RREL * 512 * DD * 2);
  __hip_bfloat16* Wt1 = (__hip_bfloat16*)alloc((size_t)RREL * 64 * 512 * 2);
  __hip_bfloat16* Wt2 = (__hip_bfloat16*)alloc((size_t)RREL * 64 * 128 * 2);
  float* Y    = (float*)alloc((size_t)MPAD * 512 * 4);
  int* deg6   = (int*)alloc((size_t)RREL * NN * 4);
  int* off6   = (int*)alloc((size_t)RREL * NN * 4);
  int* cur6   = (int*)alloc((size_t)RREL * NN * 4);
  int* eidx6  = (int*)alloc((size_t)RREL * EE * 4);
  __hip_bfloat16* AB1 = (__hip_bfloat16*)alloc((size_t)MPAD * 512 * 2);
  __hip_bfloat16* AB2 = (__hip_bfloat16*)alloc((size_t)MPAD * 128 * 2);
  if (ofs > ws_size) return;

  k_cvt_x<<<(MPAD * DD + 255) / 256, 256, 0, stream>>>(x, Xb);
  k_repack_w<<<(RREL * 512 * DD + 255) / 256, 256, 0, stream>>>(Wl, Wr, Wt);
  k_repack_gc<<<(RREL * 64 * 512 + 255) / 256, 256, 0, stream>>>(Wrel1, Wroot1, Wt1, 512);
  k_repack_gc<<<(RREL * 64 * 128 + 255) / 256, 256, 0, stream>>>(Wrel2, Wroot2, Wt2, 128);
  hipMemsetAsync(deg6, 0, (size_t)RREL * NN * 4, stream);
  k_deg6<<<((long)RREL * EE + 255) / 256, 256, 0, stream>>>(ei, deg6);
  k_scan6<<<RREL, 1024, 0, stream>>>(deg6, off6, cur6);
  k_scatter6<<<((long)RREL * EE + 255) / 256, 256, 0, stream>>>(ei, cur6, eidx6);

  for (int r = 0; r < RREL; r++) {
    const int* srcs = ei + (size_t)r * 2 * EE;
    const int* off_ = off6 + (size_t)r * NN;
    const int* dg   = deg6 + (size_t)r * NN;
    const int* eix  = eidx6 + (size_t)r * EE;
    k_gemm<<<dim3(MPAD / 128, 4), 256, 0, stream>>>((const short*)Xb,
        (const short*)(Wt + (size_t)r * 512 * DD), Y);
    k_gat<<<NN / 4, 256, 0, stream>>>(Y, srcs, off_, dg, eix, att + r * HC, bg + r * HC, AB1);
    k_agg1<<<NN / 4, 256, 0, stream>>>(AB1, srcs, off_, dg, eix);
    k_gcgemm<512, true, true><<<MPAD / 128, 256, 0, stream>>>(
        (const short*)AB1, (const short*)(Wt1 + (size_t)r * 64 * 512),
        b1 + r * OO, (void*)AB2, 128, OO);
    k_agg2<<<NN / 4, 256, 0, stream>>>(AB2, srcs, off_, dg, eix);
    k_gcgemm<128, false, false><<<MPAD / 128, 256, 0, stream>>>(
        (const short*)AB2, (const short*)(Wt2 + (size_t)r * 64 * 128),
        b2 + r * OO, (void*)(out + (size_t)r * OO), RREL * OO, 0);
  }
}

// Round 3
// 1560.886 us; speedup vs baseline: 2.0400x; 1.3131x over previous
//
#include <hip/hip_runtime.h>
#include <hip/hip_bf16.h>
#include <math.h>

#define RREL 6
#define NN   50000
#define EE   200000
#define DD   768
#define HH   4
#define CC   64
#define HC   256
#define OO   64
#define MPAD 50048    // 391 * 128
#define SCAN_B 49     // ceil(NN/1024)

typedef __attribute__((ext_vector_type(8))) short short8;
typedef __attribute__((ext_vector_type(4))) float f32x4;
typedef __attribute__((ext_vector_type(8))) unsigned short ushort8v;
typedef __attribute__((ext_vector_type(4))) unsigned short ushort4v;

__device__ __forceinline__ float b2f(unsigned short u) {
  return __uint_as_float(((unsigned)u) << 16);
}
__device__ __forceinline__ unsigned short f2b(float f) {
  __hip_bfloat16 h = __float2bfloat16(f);
  unsigned short u;
  __builtin_memcpy(&u, &h, 2);
  return u;
}

// CK-style addrspace cast for global_load_lds (16B/lane, wave-uniform LDS base + lane*16)
__device__ __forceinline__ void gload16(const void* g, void* s) {
  typedef __attribute__((address_space(1))) void gvoid;
  typedef __attribute__((address_space(3))) void svoid;
  __builtin_amdgcn_global_load_lds((gvoid*)(unsigned long long)g,
                                   (svoid*)(unsigned long long)s, 16, 0, 0);
}

// ---------- x -> bf16 (8 elems/thread, 32B in / 16B out) ----------
__global__ __launch_bounds__(256) void k_cvt_x(const float* __restrict__ x,
                                               unsigned short* __restrict__ xb) {
  long t = (long)blockIdx.x * 256 + threadIdx.x;   // t < MPAD*DD/8; DD%8==0 so one row
  long base = t * 8;
  int row = (int)(base / DD);
  ushort8v o;
  if (row < NN) {
    float4 a = *(const float4*)(x + base);
    float4 b = *(const float4*)(x + base + 4);
    o[0] = f2b(a.x); o[1] = f2b(a.y); o[2] = f2b(a.z); o[3] = f2b(a.w);
    o[4] = f2b(b.x); o[5] = f2b(b.y); o[6] = f2b(b.z); o[7] = f2b(b.w);
  } else {
    o = (ushort8v)0;
  }
  *(ushort8v*)(xb + base) = o;
}

// ---------- LDS-tiled transpose: Wl|Wr [768][256] -> Wt[r][512][768] bf16 ----------
__global__ __launch_bounds__(256) void k_repack_w(const float* __restrict__ Wl,
                                                  const float* __restrict__ Wr,
                                                  unsigned short* __restrict__ Wt) {
  __shared__ float t[32][33];
  int k0 = blockIdx.x * 32, j0 = blockIdx.y * 32, r = blockIdx.z;
  int tx = threadIdx.x & 31, ty = threadIdx.x >> 5;   // 32 x 8
#pragma unroll
  for (int s = 0; s < 4; s++) {
    int k = k0 + ty + 8 * s, j = j0 + tx;
    float v = (j < HC) ? Wl[((long)r * DD + k) * HC + j]
                       : Wr[((long)r * DD + k) * HC + (j - HC)];
    t[ty + 8 * s][tx] = v;
  }
  __syncthreads();
#pragma unroll
  for (int s = 0; s < 4; s++) {
    int j = j0 + ty + 8 * s, k = k0 + tx;
    Wt[((long)r * 512 + j) * DD + k] = f2b(t[tx][ty + 8 * s]);
  }
}

// ---------- repack [Wrel;Wroot] -> Bt[r][64][K] bf16 (small) ----------
__global__ void k_repack_gc(const float* __restrict__ Wrel, const float* __restrict__ Wroot,
                            unsigned short* __restrict__ Bt, int K) {
  int idx = blockIdx.x * blockDim.x + threadIdx.x;
  if (idx >= RREL * 64 * K) return;
  int k = idx % K;
  int o = (idx / K) % 64;
  int r = idx / (64 * K);
  int h = K >> 1;
  float v = (k < h) ? Wrel[((long)r * h + k) * 64 + o]
                    : Wroot[((long)r * h + (k - h)) * 64 + o];
  Bt[idx] = f2b(v);
}

// ---------- big bf16 MFMA GEMM: Yb[MPAD][512] = Xb @ Wt_r^T (bf16 out) ----------
__global__ __launch_bounds__(256) void k_gemm(const short* __restrict__ A,
                                              const short* __restrict__ Bt,
                                              unsigned short* __restrict__ Yb) {
  __shared__ __align__(16) short As[128 * 32];
  __shared__ __align__(16) short Bs[128 * 32];
  int tid = threadIdx.x;
  int bm = blockIdx.x, bn = blockIdx.y;
  int lane = tid & 63, wave = tid >> 6;
  int wm = (wave & 1) * 64, wn = (wave >> 1) * 64;
  int quad = lane >> 4, l16 = lane & 15;
  f32x4 acc[4][4] = {};
  const short* Ag = A + (long)bm * 128 * DD;
  const short* Bg = Bt + (long)bn * 128 * DD;
  int lr = lane >> 2, lc = (lane & 3) * 8;
  const short* ga0 = Ag + (long)(wave * 16 + lr) * DD + lc;
  const short* ga1 = Ag + (long)(64 + wave * 16 + lr) * DD + lc;
  const short* gb0 = Bg + (long)(wave * 16 + lr) * DD + lc;
  const short* gb1 = Bg + (long)(64 + wave * 16 + lr) * DD + lc;
  short* la0 = &As[(wave * 16) * 32];
  short* la1 = &As[(64 + wave * 16) * 32];
  short* lb0 = &Bs[(wave * 16) * 32];
  short* lb1 = &Bs[(64 + wave * 16) * 32];
  for (int k0 = 0; k0 < DD; k0 += 32) {
    gload16(ga0 + k0, la0);
    gload16(ga1 + k0, la1);
    gload16(gb0 + k0, lb0);
    gload16(gb1 + k0, lb1);
    __syncthreads();
    short8 af[4], bf[4];
#pragma unroll
    for (int i = 0; i < 4; i++) af[i] = *(const short8*)&As[(wm + i * 16 + l16) * 32 + quad * 8];
#pragma unroll
    for (int j = 0; j < 4; j++) bf[j] = *(const short8*)&Bs[(wn + j * 16 + l16) * 32 + quad * 8];
#pragma unroll
    for (int i = 0; i < 4; i++)
#pragma unroll
      for (int j = 0; j < 4; j++)
        acc[i][j] = __builtin_amdgcn_mfma_f32_16x16x32_bf16(af[i], bf[j], acc[i][j], 0, 0, 0);
    __syncthreads();
  }
#pragma unroll
  for (int i = 0; i < 4; i++)
#pragma unroll
    for (int j = 0; j < 4; j++)
#pragma unroll
      for (int reg = 0; reg < 4; reg++) {
        int row = bm * 128 + wm + i * 16 + quad * 4 + reg;
        int col = bn * 128 + wn + j * 16 + l16;
        Yb[(long)row * 512 + col] = f2b(acc[i][j][reg]);
      }
}

// ---------- small-N MFMA GEMM for GraphConv: out = A[MPAD][K] @ Bt[64][K]^T ----------
template <int K, bool RELU, bool OBF16>
__global__ __launch_bounds__(256) void k_gcgemm(const short* __restrict__ A,
                                                const short* __restrict__ Bt,
                                                const float* __restrict__ bias,
                                                void* __restrict__ outp, long ldo, int ocol) {
  __shared__ __align__(16) short As[128 * 32];
  __shared__ __align__(16) short Bs[64 * 32];
  int tid = threadIdx.x;
  int bm = blockIdx.x;
  int lane = tid & 63, wave = tid >> 6;
  int quad = lane >> 4, l16 = lane & 15;
  f32x4 acc[2][4] = {};
  const short* Ag = A + (long)bm * 128 * K;
  int lr = lane >> 2, lc = (lane & 3) * 8;
  const short* ga0 = Ag + (long)(wave * 16 + lr) * K + lc;
  const short* ga1 = Ag + (long)(64 + wave * 16 + lr) * K + lc;
  const short* gb0 = Bt + (long)(wave * 16 + lr) * K + lc;
  short* la0 = &As[(wave * 16) * 32];
  short* la1 = &As[(64 + wave * 16) * 32];
  short* lb0 = &Bs[(wave * 16) * 32];
  for (int k0 = 0; k0 < K; k0 += 32) {
    gload16(ga0 + k0, la0);
    gload16(ga1 + k0, la1);
    gload16(gb0 + k0, lb0);
    __syncthreads();
    short8 af[2], bf[4];
#pragma unroll
    for (int i = 0; i < 2; i++) af[i] = *(const short8*)&As[(wave * 32 + i * 16 + l16) * 32 + quad * 8];
#pragma unroll
    for (int j = 0; j < 4; j++) bf[j] = *(const short8*)&Bs[(j * 16 + l16) * 32 + quad * 8];
#pragma unroll
    for (int i = 0; i < 2; i++)
#pragma unroll
      for (int j = 0; j < 4; j++)
        acc[i][j] = __builtin_amdgcn_mfma_f32_16x16x32_bf16(af[i], bf[j], acc[i][j], 0, 0, 0);
    __syncthreads();
  }
#pragma unroll
  for (int i = 0; i < 2; i++)
#pragma unroll
    for (int j = 0; j < 4; j++)
#pragma unroll
      for (int reg = 0; reg < 4; reg++) {
        int row = bm * 128 + wave * 32 + i * 16 + quad * 4 + reg;
        int col = j * 16 + l16;
        float v = acc[i][j][reg] + bias[col];
        if (RELU) v = fmaxf(v, 0.f);
        if (OBF16) {
          ((unsigned short*)outp)[(long)row * ldo + ocol + col] = f2b(v);
        } else {
          if (row < NN) ((float*)outp)[(long)row * ldo + ocol + col] = v;
        }
      }
}

// ---------- batched CSR build ----------
__global__ void k_deg6(const int* __restrict__ ei, int* __restrict__ deg6) {
  long e = (long)blockIdx.x * blockDim.x + threadIdx.x;
  if (e >= (long)RREL * EE) return;
  int r = e / EE, i = e % EE;
  int t = ei[(long)r * 2 * EE + EE + i];
  atomicAdd(&deg6[(long)r * NN + t], 1);
}

__global__ __launch_bounds__(256) void k_bsum(const int* __restrict__ deg6, int* __restrict__ bsum) {
  int r = blockIdx.y, b = blockIdx.x, tid = threadIdx.x;
  const int* deg = deg6 + (long)r * NN;
  int i0 = b * 1024 + tid * 4;
  int s = 0;
#pragma unroll
  for (int j = 0; j < 4; j++) { int i = i0 + j; if (i < NN) s += deg[i]; }
#pragma unroll
  for (int m = 1; m < 64; m <<= 1) s += __shfl_xor(s, m);
  __shared__ int ws[4];
  if ((tid & 63) == 0) ws[tid >> 6] = s;
  __syncthreads();
  if (tid == 0) bsum[r * SCAN_B + b] = ws[0] + ws[1] + ws[2] + ws[3];
}

__global__ void k_bscan(int* __restrict__ bsum) {   // 1 block, 384 thr = 6 waves
  int w = threadIdx.x >> 6, l = threadIdx.x & 63;
  int v = (l < SCAN_B) ? bsum[w * SCAN_B + l] : 0;
  int incl = v;
#pragma unroll
  for (int d = 1; d < 64; d <<= 1) { int t = __shfl_up(incl, d); if (l >= d) incl += t; }
  if (l < SCAN_B) bsum[w * SCAN_B + l] = incl - v;   // exclusive
}

__global__ __launch_bounds__(256) void k_boff(const int* __restrict__ deg6, const int* __restrict__ bsum,
                                              int* __restrict__ off6, int* __restrict__ cur6) {
  int r = blockIdx.y, b = blockIdx.x, tid = threadIdx.x;
  const int* deg = deg6 + (long)r * NN;
  int i0 = b * 1024 + tid * 4;
  int v[4], s = 0;
#pragma unroll
  for (int j = 0; j < 4; j++) { int i = i0 + j; v[j] = (i < NN) ? deg[i] : 0; s += v[j]; }
  int l = tid & 63, wv = tid >> 6;
  int incl = s;
#pragma unroll
  for (int d = 1; d < 64; d <<= 1) { int t = __shfl_up(incl, d); if (l >= d) incl += t; }
  __shared__ int ws[4];
  if (l == 63) ws[wv] = incl;
  __syncthreads();
  int pre = incl - s;
  for (int k = 0; k < wv; k++) pre += ws[k];
  pre += bsum[r * SCAN_B + b];
  int e0 = pre;
#pragma unroll
  for (int j = 0; j < 4; j++) {
    int i = i0 + j;
    if (i < NN) { off6[(long)r * NN + i] = e0; cur6[(long)r * NN + i] = e0; }
    e0 += v[j];
  }
}

// scatter writes the SOURCE id directly (no eidx indirection downstream)
__global__ void k_scatter6(const int* __restrict__ ei, int* __restrict__ cur6,
                           int* __restrict__ ssrc6) {
  long e = (long)blockIdx.x * blockDim.x + threadIdx.x;
  if (e >= (long)RREL * EE) return;
  int r = e / EE, i = e % EE;
  int src = ei[(long)r * 2 * EE + i];
  int t   = ei[(long)r * 2 * EE + EE + i];
  int p = atomicAdd(&cur6[(long)r * NN + t], 1);
  ssrc6[(long)r * EE + p] = src;
}

// ---------- fused GATv2: wave per target node, lane = 4 consecutive channels ----------
__global__ __launch_bounds__(256) void k_gat(const unsigned short* __restrict__ Y,
                                             const int* __restrict__ ssrc,
                                             const int* __restrict__ off, const int* __restrict__ deg,
                                             const float* __restrict__ att, const float* __restrict__ bg,
                                             unsigned short* __restrict__ AB1) {
  int l = threadIdx.x & 63;
  int n = blockIdx.x * 4 + (threadIdx.x >> 6);
  if (n >= NN) return;
  const unsigned short* yb = Y + (long)n * 512;
  ushort4v xlv = *(const ushort4v*)(yb + 4 * l);
  ushort4v xrv = *(const ushort4v*)(yb + 256 + 4 * l);
  float xl[4], xr[4];
#pragma unroll
  for (int j = 0; j < 4; j++) { xl[j] = b2f(xlv[j]); xr[j] = b2f(xrv[j]); }
  float4 at4 = *(const float4*)(att + 4 * l);
  float at[4] = {at4.x, at4.y, at4.z, at4.w};
  float num[4] = {0.f, 0.f, 0.f, 0.f}, den = 0.f;
  int st = off[n], cnt = deg[n];
  for (int i = -1; i < cnt; i++) {   // i == -1 is the self loop
    float xv[4];
    if (i < 0) {
#pragma unroll
      for (int j = 0; j < 4; j++) xv[j] = xl[j];
    } else {
      int s = ssrc[st + i];
      ushort4v v = *(const ushort4v*)(Y + (long)s * 512 + 4 * l);
#pragma unroll
      for (int j = 0; j < 4; j++) xv[j] = b2f(v[j]);
    }
    float lg = 0.f;
#pragma unroll
    for (int j = 0; j < 4; j++) {
      float e = xv[j] + xr[j];
      e = e > 0.f ? e : 0.2f * e;
      lg += at[j] * e;
    }
    lg += __shfl_xor(lg, 1); lg += __shfl_xor(lg, 2);
    lg += __shfl_xor(lg, 4); lg += __shfl_xor(lg, 8);   // head group = 16 lanes
    float a = expf(lg);
    den += a;
#pragma unroll
    for (int j = 0; j < 4; j++) num[j] += a * xv[j];
  }
  float4 bg4 = *(const float4*)(bg + 4 * l);
  float bgj[4] = {bg4.x, bg4.y, bg4.z, bg4.w};
  ushort4v o;
  float inv = 1.f / (den + 1e-16f);
#pragma unroll
  for (int j = 0; j < 4; j++) o[j] = f2b(fmaxf(num[j] * inv + bgj[j], 0.f));
  *(ushort4v*)(AB1 + (long)n * 512 + 256 + 4 * l) = o;
}

// ---------- CSR gather-sum of h1 (bf16x4 per lane) ----------
__global__ __launch_bounds__(256) void k_agg1(unsigned short* __restrict__ AB1,
                                              const int* __restrict__ ssrc,
                                              const int* __restrict__ off, const int* __restrict__ deg) {
  int l = threadIdx.x & 63;
  int n = blockIdx.x * 4 + (threadIdx.x >> 6);
  if (n >= NN) return;
  float acc[4] = {0.f, 0.f, 0.f, 0.f};
  int st = off[n], cnt = deg[n];
  for (int i = 0; i < cnt; i++) {
    int s = ssrc[st + i];
    ushort4v v = *(const ushort4v*)(AB1 + (long)s * 512 + 256 + 4 * l);
#pragma unroll
    for (int j = 0; j < 4; j++) acc[j] += b2f(v[j]);
  }
  ushort4v o;
#pragma unroll
  for (int j = 0; j < 4; j++) o[j] = f2b(acc[j]);
  *(ushort4v*)(AB1 + (long)n * 512 + 4 * l) = o;
}

// ---------- CSR gather-sum of h2 ----------
__global__ __launch_bounds__(256) void k_agg2(unsigned short* __restrict__ AB2,
                                              const int* __restrict__ ssrc,
                                              const int* __restrict__ off, const int* __restrict__ deg) {
  int l = threadIdx.x & 63;
  int n = blockIdx.x * 4 + (threadIdx.x >> 6);
  if (n >= NN) return;
  float acc = 0.f;
  int st = off[n], cnt = deg[n];
  for (int i = 0; i < cnt; i++) {
    int s = ssrc[st + i];
    acc += b2f(AB2[(long)s * 128 + OO + l]);
  }
  AB2[(long)n * 128 + l] = f2b(acc);
}

extern "C" void kernel_launch(void* const* d_in, const int* in_sizes, int n_in,
                              void* d_out, int out_size, void* d_ws, size_t ws_size,
                              hipStream_t stream) {
  (void)in_sizes; (void)n_in; (void)out_size;
  const float* x      = (const float*)d_in[0];
  const int*   ei     = (const int*)d_in[1];
  const float* Wl     = (const float*)d_in[2];
  const float* Wr     = (const float*)d_in[3];
  const float* att    = (const float*)d_in[4];
  const float* bg     = (const float*)d_in[5];
  const float* Wrel1  = (const float*)d_in[6];
  const float* Wroot1 = (const float*)d_in[7];
  const float* b1     = (const float*)d_in[8];
  const float* Wrel2  = (const float*)d_in[9];
  const float* Wroot2 = (const float*)d_in[10];
  const float* b2     = (const float*)d_in[11];
  float* out = (float*)d_out;

  char* ws = (char*)d_ws;
  size_t ofs = 0;
  auto alloc = [&](size_t bytes) {
    char* p = ws + ofs;
    ofs += (bytes + 255) & ~(size_t)255;
    return p;
  };
  unsigned short* Xb  = (unsigned short*)alloc((size_t)MPAD * DD * 2);
  unsigned short* Wt  = (unsigned short*)alloc((size_t)RREL * 512 * DD * 2);
  unsigned short* Wt1 = (unsigned short*)alloc((size_t)RREL * 64 * 512 * 2);
  unsigned short* Wt2 = (unsigned short*)alloc((size_t)RREL * 64 * 128 * 2);
  unsigned short* Yb  = (unsigned short*)alloc((size_t)MPAD * 512 * 2);
  int* deg6   = (int*)alloc((size_t)RREL * NN * 4);
  int* off6   = (int*)alloc((size_t)RREL * NN * 4);
  int* cur6   = (int*)alloc((size_t)RREL * NN * 4);
  int* bsum   = (int*)alloc((size_t)RREL * SCAN_B * 4);
  int* ssrc6  = (int*)alloc((size_t)RREL * EE * 4);
  unsigned short* AB1 = (unsigned short*)alloc((size_t)MPAD * 512 * 2);
  unsigned short* AB2 = (unsigned short*)alloc((size_t)MPAD * 128 * 2);
  if (ofs > ws_size) return;

  k_cvt_x<<<(int)((long)MPAD * DD / 8 / 256), 256, 0, stream>>>(x, Xb);
  k_repack_w<<<dim3(DD / 32, 512 / 32, RREL), 256, 0, stream>>>(Wl, Wr, Wt);
  k_repack_gc<<<(RREL * 64 * 512 + 255) / 256, 256, 0, stream>>>(Wrel1, Wroot1, Wt1, 512);
  k_repack_gc<<<(RREL * 64 * 128 + 255) / 256, 256, 0, stream>>>(Wrel2, Wroot2, Wt2, 128);
  hipMemsetAsync(deg6, 0, (size_t)RREL * NN * 4, stream);
  k_deg6<<<((long)RREL * EE + 255) / 256, 256, 0, stream>>>(ei, deg6);
  k_bsum<<<dim3(SCAN_B, RREL), 256, 0, stream>>>(deg6, bsum);
  k_bscan<<<1, 384, 0, stream>>>(bsum);
  k_boff<<<dim3(SCAN_B, RREL), 256, 0, stream>>>(deg6, bsum, off6, cur6);
  k_scatter6<<<((long)RREL * EE + 255) / 256, 256, 0, stream>>>(ei, cur6, ssrc6);

  for (int r = 0; r < RREL; r++) {
    const int* off_ = off6 + (size_t)r * NN;
    const int* dg   = deg6 + (size_t)r * NN;
    const int* ssrc = ssrc6 + (size_t)r * EE;
    k_gemm<<<dim3(MPAD / 128, 4), 256, 0, stream>>>((const short*)Xb,
        (const short*)(Wt + (size_t)r * 512 * DD), Yb);
    k_gat<<<NN / 4, 256, 0, stream>>>(Yb, ssrc, off_, dg, att + r * HC, bg + r * HC, AB1);
    k_agg1<<<NN / 4, 256, 0, stream>>>(AB1, ssrc, off_, dg);
    k_gcgemm<512, true, true><<<MPAD / 128, 256, 0, stream>>>(
        (const short*)AB1, (const short*)(Wt1 + (size_t)r * 64 * 512),
        b1 + r * OO, (void*)AB2, 128, OO);
    k_agg2<<<NN / 4, 256, 0, stream>>>(AB2, ssrc, off_, dg);
    k_gcgemm<128, false, false><<<MPAD / 128, 256, 0, stream>>>(
        (const short*)AB2, (const short*)(Wt2 + (size_t)r * 64 * 128),
        b2 + r * OO, (void*)(out + (size_t)r * OO), RREL * OO, 0);
  }
}

// Round 4
// 1281.667 us; speedup vs baseline: 2.4845x; 1.2179x over previous
//
#include <hip/hip_runtime.h>
#include <hip/hip_bf16.h>
#include <math.h>

#define RREL 6
#define NN   50000
#define EE   200000
#define DD   768
#define HH   4
#define CC   64
#define HC   256
#define OO   64
#define MPAD 50048    // 391 * 128
#define SCAN_B 49     // ceil(NN/1024)

typedef __attribute__((ext_vector_type(8))) short short8;
typedef __attribute__((ext_vector_type(4))) float f32x4;
typedef __attribute__((ext_vector_type(8))) unsigned short ushort8v;
typedef __attribute__((ext_vector_type(4))) unsigned short ushort4v;

__device__ __forceinline__ float b2f(unsigned short u) {
  return __uint_as_float(((unsigned)u) << 16);
}
__device__ __forceinline__ unsigned short f2b(float f) {
  __hip_bfloat16 h = __float2bfloat16(f);
  unsigned short u;
  __builtin_memcpy(&u, &h, 2);
  return u;
}

// global_load_lds, 16B/lane, wave-uniform LDS base + lane*16
__device__ __forceinline__ void gload16(const void* g, void* s) {
  typedef __attribute__((address_space(1))) void gvoid;
  typedef __attribute__((address_space(3))) void svoid;
  __builtin_amdgcn_global_load_lds((gvoid*)(unsigned long long)g,
                                   (svoid*)(unsigned long long)s, 16, 0, 0);
}

// ---------- x -> bf16 (8 elems/thread) ----------
__global__ __launch_bounds__(256) void k_cvt_x(const float* __restrict__ x,
                                               unsigned short* __restrict__ xb) {
  long t = (long)blockIdx.x * 256 + threadIdx.x;
  long base = t * 8;
  int row = (int)(base / DD);
  ushort8v o;
  if (row < NN) {
    float4 a = *(const float4*)(x + base);
    float4 b = *(const float4*)(x + base + 4);
    o[0] = f2b(a.x); o[1] = f2b(a.y); o[2] = f2b(a.z); o[3] = f2b(a.w);
    o[4] = f2b(b.x); o[5] = f2b(b.y); o[6] = f2b(b.z); o[7] = f2b(b.w);
  } else {
    o = (ushort8v)0;
  }
  *(ushort8v*)(xb + base) = o;
}

// ---------- LDS-tiled transpose: Wl|Wr [768][256] -> Wt[r*512+j][768] bf16 ----------
__global__ __launch_bounds__(256) void k_repack_w(const float* __restrict__ Wl,
                                                  const float* __restrict__ Wr,
                                                  unsigned short* __restrict__ Wt) {
  __shared__ float t[32][33];
  int k0 = blockIdx.x * 32, j0 = blockIdx.y * 32, r = blockIdx.z;
  int tx = threadIdx.x & 31, ty = threadIdx.x >> 5;
#pragma unroll
  for (int s = 0; s < 4; s++) {
    int k = k0 + ty + 8 * s, j = j0 + tx;
    float v = (j < HC) ? Wl[((long)r * DD + k) * HC + j]
                       : Wr[((long)r * DD + k) * HC + (j - HC)];
    t[ty + 8 * s][tx] = v;
  }
  __syncthreads();
#pragma unroll
  for (int s = 0; s < 4; s++) {
    int j = j0 + ty + 8 * s, k = k0 + tx;
    Wt[((long)r * 512 + j) * DD + k] = f2b(t[tx][ty + 8 * s]);
  }
}

// ---------- repack [Wrel;Wroot] -> Bt[r][64][K] bf16 ----------
__global__ void k_repack_gc(const float* __restrict__ Wrel, const float* __restrict__ Wroot,
                            unsigned short* __restrict__ Bt, int K) {
  int idx = blockIdx.x * blockDim.x + threadIdx.x;
  if (idx >= RREL * 64 * K) return;
  int k = idx % K;
  int o = (idx / K) % 64;
  int r = idx / (64 * K);
  int h = K >> 1;
  float v = (k < h) ? Wrel[((long)r * h + k) * 64 + o]
                    : Wroot[((long)r * h + (k - h)) * 64 + o];
  Bt[idx] = f2b(v);
}

// ---------- fused GEMM for all 6 relations: Yall[r][MPAD][512] = Xb @ Wt_all^T ----------
__global__ __launch_bounds__(256) void k_gemm(const short* __restrict__ A,
                                              const short* __restrict__ Bt,
                                              unsigned short* __restrict__ Yall) {
  __shared__ __align__(16) short As[128 * 32];
  __shared__ __align__(16) short Bs[128 * 32];
  int tid = threadIdx.x;
  int bm = blockIdx.x, bn = blockIdx.y;   // bn in [0,24): rel = bn>>2
  int lane = tid & 63, wave = tid >> 6;
  int wm = (wave & 1) * 64, wn = (wave >> 1) * 64;
  int quad = lane >> 4, l16 = lane & 15;
  f32x4 acc[4][4] = {};
  const short* Ag = A + (long)bm * 128 * DD;
  const short* Bg = Bt + (long)bn * 128 * DD;
  int lr = lane >> 2, lc = (lane & 3) * 8;
  const short* ga0 = Ag + (long)(wave * 16 + lr) * DD + lc;
  const short* ga1 = Ag + (long)(64 + wave * 16 + lr) * DD + lc;
  const short* gb0 = Bg + (long)(wave * 16 + lr) * DD + lc;
  const short* gb1 = Bg + (long)(64 + wave * 16 + lr) * DD + lc;
  short* la0 = &As[(wave * 16) * 32];
  short* la1 = &As[(64 + wave * 16) * 32];
  short* lb0 = &Bs[(wave * 16) * 32];
  short* lb1 = &Bs[(64 + wave * 16) * 32];
  for (int k0 = 0; k0 < DD; k0 += 32) {
    gload16(ga0 + k0, la0);
    gload16(ga1 + k0, la1);
    gload16(gb0 + k0, lb0);
    gload16(gb1 + k0, lb1);
    __syncthreads();
    short8 af[4], bf[4];
#pragma unroll
    for (int i = 0; i < 4; i++) af[i] = *(const short8*)&As[(wm + i * 16 + l16) * 32 + quad * 8];
#pragma unroll
    for (int j = 0; j < 4; j++) bf[j] = *(const short8*)&Bs[(wn + j * 16 + l16) * 32 + quad * 8];
#pragma unroll
    for (int i = 0; i < 4; i++)
#pragma unroll
      for (int j = 0; j < 4; j++)
        acc[i][j] = __builtin_amdgcn_mfma_f32_16x16x32_bf16(af[i], bf[j], acc[i][j], 0, 0, 0);
    __syncthreads();
  }
  int rrel = bn >> 2;
  unsigned short* Yr = Yall + (long)rrel * MPAD * 512;
  int cb = (bn & 3) * 128 + wn;
#pragma unroll
  for (int i = 0; i < 4; i++)
#pragma unroll
    for (int j = 0; j < 4; j++)
#pragma unroll
      for (int reg = 0; reg < 4; reg++) {
        int row = bm * 128 + wm + i * 16 + quad * 4 + reg;
        int col = cb + j * 16 + l16;
        Yr[(long)row * 512 + col] = f2b(acc[i][j][reg]);
      }
}

// ---------- batched small-N MFMA GEMM for GraphConv (blockIdx.y = relation) ----------
template <int K, bool RELU, bool OBF16>
__global__ __launch_bounds__(256) void k_gcgemm(const short* __restrict__ Aall,
                                                const short* __restrict__ Btall,
                                                const float* __restrict__ biasall,
                                                void* __restrict__ outp, long ldo, int ocol,
                                                long orelstride) {
  __shared__ __align__(16) short As[128 * 32];
  __shared__ __align__(16) short Bs[64 * 32];
  int tid = threadIdx.x;
  int bm = blockIdx.x, r = blockIdx.y;
  const short* A  = Aall + (long)r * MPAD * K;
  const short* Bt = Btall + (long)r * 64 * K;
  const float* bias = biasall + (long)r * 64;
  int lane = tid & 63, wave = tid >> 6;
  int quad = lane >> 4, l16 = lane & 15;
  f32x4 acc[2][4] = {};
  const short* Ag = A + (long)bm * 128 * K;
  int lr = lane >> 2, lc = (lane & 3) * 8;
  const short* ga0 = Ag + (long)(wave * 16 + lr) * K + lc;
  const short* ga1 = Ag + (long)(64 + wave * 16 + lr) * K + lc;
  const short* gb0 = Bt + (long)(wave * 16 + lr) * K + lc;
  short* la0 = &As[(wave * 16) * 32];
  short* la1 = &As[(64 + wave * 16) * 32];
  short* lb0 = &Bs[(wave * 16) * 32];
  for (int k0 = 0; k0 < K; k0 += 32) {
    gload16(ga0 + k0, la0);
    gload16(ga1 + k0, la1);
    gload16(gb0 + k0, lb0);
    __syncthreads();
    short8 af[2], bf[4];
#pragma unroll
    for (int i = 0; i < 2; i++) af[i] = *(const short8*)&As[(wave * 32 + i * 16 + l16) * 32 + quad * 8];
#pragma unroll
    for (int j = 0; j < 4; j++) bf[j] = *(const short8*)&Bs[(j * 16 + l16) * 32 + quad * 8];
#pragma unroll
    for (int i = 0; i < 2; i++)
#pragma unroll
      for (int j = 0; j < 4; j++)
        acc[i][j] = __builtin_amdgcn_mfma_f32_16x16x32_bf16(af[i], bf[j], acc[i][j], 0, 0, 0);
    __syncthreads();
  }
#pragma unroll
  for (int i = 0; i < 2; i++)
#pragma unroll
    for (int j = 0; j < 4; j++)
#pragma unroll
      for (int reg = 0; reg < 4; reg++) {
        int row = bm * 128 + wave * 32 + i * 16 + quad * 4 + reg;
        int col = j * 16 + l16;
        float v = acc[i][j][reg] + bias[col];
        if (RELU) v = fmaxf(v, 0.f);
        if (OBF16) {
          ((unsigned short*)outp)[(long)r * orelstride + (long)row * ldo + ocol + col] = f2b(v);
        } else {
          if (row < NN) ((float*)outp)[(long)r * orelstride + (long)row * ldo + ocol + col] = v;
        }
      }
}

// ---------- batched CSR build ----------
__global__ void k_deg6(const int* __restrict__ ei, int* __restrict__ deg6) {
  long e = (long)blockIdx.x * blockDim.x + threadIdx.x;
  if (e >= (long)RREL * EE) return;
  int r = e / EE, i = e % EE;
  int t = ei[(long)r * 2 * EE + EE + i];
  atomicAdd(&deg6[(long)r * NN + t], 1);
}

__global__ __launch_bounds__(256) void k_bsum(const int* __restrict__ deg6, int* __restrict__ bsum) {
  int r = blockIdx.y, b = blockIdx.x, tid = threadIdx.x;
  const int* deg = deg6 + (long)r * NN;
  int i0 = b * 1024 + tid * 4;
  int s = 0;
#pragma unroll
  for (int j = 0; j < 4; j++) { int i = i0 + j; if (i < NN) s += deg[i]; }
#pragma unroll
  for (int m = 1; m < 64; m <<= 1) s += __shfl_xor(s, m);
  __shared__ int ws[4];
  if ((tid & 63) == 0) ws[tid >> 6] = s;
  __syncthreads();
  if (tid == 0) bsum[r * SCAN_B + b] = ws[0] + ws[1] + ws[2] + ws[3];
}

__global__ void k_bscan(int* __restrict__ bsum) {   // 1 block, 384 thr = 6 waves
  int w = threadIdx.x >> 6, l = threadIdx.x & 63;
  int v = (l < SCAN_B) ? bsum[w * SCAN_B + l] : 0;
  int incl = v;
#pragma unroll
  for (int d = 1; d < 64; d <<= 1) { int t = __shfl_up(incl, d); if (l >= d) incl += t; }
  if (l < SCAN_B) bsum[w * SCAN_B + l] = incl - v;   // exclusive
}

__global__ __launch_bounds__(256) void k_boff(const int* __restrict__ deg6, const int* __restrict__ bsum,
                                              int* __restrict__ off6, int* __restrict__ cur6) {
  int r = blockIdx.y, b = blockIdx.x, tid = threadIdx.x;
  const int* deg = deg6 + (long)r * NN;
  int i0 = b * 1024 + tid * 4;
  int v[4], s = 0;
#pragma unroll
  for (int j = 0; j < 4; j++) { int i = i0 + j; v[j] = (i < NN) ? deg[i] : 0; s += v[j]; }
  int l = tid & 63, wv = tid >> 6;
  int incl = s;
#pragma unroll
  for (int d = 1; d < 64; d <<= 1) { int t = __shfl_up(incl, d); if (l >= d) incl += t; }
  __shared__ int ws[4];
  if (l == 63) ws[wv] = incl;
  __syncthreads();
  int pre = incl - s;
  for (int k = 0; k < wv; k++) pre += ws[k];
  pre += bsum[r * SCAN_B + b];
  int e0 = pre;
#pragma unroll
  for (int j = 0; j < 4; j++) {
    int i = i0 + j;
    if (i < NN) { off6[(long)r * NN + i] = e0; cur6[(long)r * NN + i] = e0; }
    e0 += v[j];
  }
}

__global__ void k_scatter6(const int* __restrict__ ei, int* __restrict__ cur6,
                           int* __restrict__ ssrc6) {
  long e = (long)blockIdx.x * blockDim.x + threadIdx.x;
  if (e >= (long)RREL * EE) return;
  int r = e / EE, i = e % EE;
  int src = ei[(long)r * 2 * EE + i];
  int t   = ei[(long)r * 2 * EE + EE + i];
  int p = atomicAdd(&cur6[(long)r * NN + t], 1);
  ssrc6[(long)r * EE + p] = src;
}

// ---------- batched fused GATv2 (blockIdx.y = r); h1 overwrites Y[:,256:512] ----------
__global__ __launch_bounds__(256) void k_gat(unsigned short* __restrict__ Yall,
                                             const int* __restrict__ ssrc6,
                                             const int* __restrict__ off6, const int* __restrict__ deg6,
                                             const float* __restrict__ attall,
                                             const float* __restrict__ bgall) {
  int r = blockIdx.y;
  unsigned short* Y = Yall + (long)r * MPAD * 512;
  const int* ssrc = ssrc6 + (long)r * EE;
  const float* att = attall + r * HC;
  const float* bg  = bgall + r * HC;
  int l = threadIdx.x & 63;
  int n = blockIdx.x * 4 + (threadIdx.x >> 6);
  if (n >= NN) return;
  const unsigned short* yb = Y + (long)n * 512;
  ushort4v xlv = *(const ushort4v*)(yb + 4 * l);
  ushort4v xrv = *(const ushort4v*)(yb + 256 + 4 * l);
  float xl[4], xr[4];
#pragma unroll
  for (int j = 0; j < 4; j++) { xl[j] = b2f(xlv[j]); xr[j] = b2f(xrv[j]); }
  float4 at4 = *(const float4*)(att + 4 * l);
  float at[4] = {at4.x, at4.y, at4.z, at4.w};
  float num[4] = {0.f, 0.f, 0.f, 0.f}, den = 0.f;
  // self loop
  {
    float lg = 0.f;
#pragma unroll
    for (int j = 0; j < 4; j++) {
      float e = xl[j] + xr[j];
      e = e > 0.f ? e : 0.2f * e;
      lg += at[j] * e;
    }
    lg += __shfl_xor(lg, 1); lg += __shfl_xor(lg, 2);
    lg += __shfl_xor(lg, 4); lg += __shfl_xor(lg, 8);
    float a = expf(lg);
    den += a;
#pragma unroll
    for (int j = 0; j < 4; j++) num[j] += a * xl[j];
  }
  int st = off6[(long)r * NN + n], cnt = deg6[(long)r * NN + n];
  int i = 0;
  for (; i + 2 <= cnt; i += 2) {   // 2-way unroll: two gathers in flight
    int s0 = ssrc[st + i], s1 = ssrc[st + i + 1];
    ushort4v v0 = *(const ushort4v*)(Y + (long)s0 * 512 + 4 * l);
    ushort4v v1 = *(const ushort4v*)(Y + (long)s1 * 512 + 4 * l);
    float x0[4], x1[4];
#pragma unroll
    for (int j = 0; j < 4; j++) { x0[j] = b2f(v0[j]); x1[j] = b2f(v1[j]); }
    float lg0 = 0.f, lg1 = 0.f;
#pragma unroll
    for (int j = 0; j < 4; j++) {
      float e0 = x0[j] + xr[j]; e0 = e0 > 0.f ? e0 : 0.2f * e0; lg0 += at[j] * e0;
      float e1 = x1[j] + xr[j]; e1 = e1 > 0.f ? e1 : 0.2f * e1; lg1 += at[j] * e1;
    }
    lg0 += __shfl_xor(lg0, 1); lg1 += __shfl_xor(lg1, 1);
    lg0 += __shfl_xor(lg0, 2); lg1 += __shfl_xor(lg1, 2);
    lg0 += __shfl_xor(lg0, 4); lg1 += __shfl_xor(lg1, 4);
    lg0 += __shfl_xor(lg0, 8); lg1 += __shfl_xor(lg1, 8);
    float a0 = expf(lg0), a1 = expf(lg1);
    den += a0 + a1;
#pragma unroll
    for (int j = 0; j < 4; j++) num[j] += a0 * x0[j] + a1 * x1[j];
  }
  if (i < cnt) {
    int s0 = ssrc[st + i];
    ushort4v v0 = *(const ushort4v*)(Y + (long)s0 * 512 + 4 * l);
    float x0[4];
#pragma unroll
    for (int j = 0; j < 4; j++) x0[j] = b2f(v0[j]);
    float lg = 0.f;
#pragma unroll
    for (int j = 0; j < 4; j++) {
      float e = x0[j] + xr[j];
      e = e > 0.f ? e : 0.2f * e;
      lg += at[j] * e;
    }
    lg += __shfl_xor(lg, 1); lg += __shfl_xor(lg, 2);
    lg += __shfl_xor(lg, 4); lg += __shfl_xor(lg, 8);
    float a = expf(lg);
    den += a;
#pragma unroll
    for (int j = 0; j < 4; j++) num[j] += a * x0[j];
  }
  float4 bg4 = *(const float4*)(bg + 4 * l);
  float bgj[4] = {bg4.x, bg4.y, bg4.z, bg4.w};
  ushort4v o;
  float inv = 1.f / (den + 1e-16f);
#pragma unroll
  for (int j = 0; j < 4; j++) o[j] = f2b(fmaxf(num[j] * inv + bgj[j], 0.f));
  *(ushort4v*)(Y + (long)n * 512 + 256 + 4 * l) = o;   // h1 over dead xr
}

// ---------- batched CSR gather-sum of h1; agg over dead xl half ----------
__global__ __launch_bounds__(256) void k_agg1(unsigned short* __restrict__ Yall,
                                              const int* __restrict__ ssrc6,
                                              const int* __restrict__ off6,
                                              const int* __restrict__ deg6) {
  int r = blockIdx.y;
  unsigned short* Y = Yall + (long)r * MPAD * 512;
  const int* ssrc = ssrc6 + (long)r * EE;
  int l = threadIdx.x & 63;
  int n = blockIdx.x * 4 + (threadIdx.x >> 6);
  if (n >= NN) return;
  float acc[4] = {0.f, 0.f, 0.f, 0.f};
  int st = off6[(long)r * NN + n], cnt = deg6[(long)r * NN + n];
  int i = 0;
  for (; i + 4 <= cnt; i += 4) {
    int s0 = ssrc[st + i], s1 = ssrc[st + i + 1], s2 = ssrc[st + i + 2], s3 = ssrc[st + i + 3];
    ushort4v v0 = *(const ushort4v*)(Y + (long)s0 * 512 + 256 + 4 * l);
    ushort4v v1 = *(const ushort4v*)(Y + (long)s1 * 512 + 256 + 4 * l);
    ushort4v v2 = *(const ushort4v*)(Y + (long)s2 * 512 + 256 + 4 * l);
    ushort4v v3 = *(const ushort4v*)(Y + (long)s3 * 512 + 256 + 4 * l);
#pragma unroll
    for (int j = 0; j < 4; j++)
      acc[j] += b2f(v0[j]) + b2f(v1[j]) + b2f(v2[j]) + b2f(v3[j]);
  }
  for (; i < cnt; i++) {
    int s = ssrc[st + i];
    ushort4v v = *(const ushort4v*)(Y + (long)s * 512 + 256 + 4 * l);
#pragma unroll
    for (int j = 0; j < 4; j++) acc[j] += b2f(v[j]);
  }
  ushort4v o;
#pragma unroll
  for (int j = 0; j < 4; j++) o[j] = f2b(acc[j]);
  *(ushort4v*)(Y + (long)n * 512 + 4 * l) = o;
}

// ---------- batched CSR gather-sum of h2 ----------
__global__ __launch_bounds__(256) void k_agg2(unsigned short* __restrict__ ABall,
                                              const int* __restrict__ ssrc6,
                                              const int* __restrict__ off6,
                                              const int* __restrict__ deg6) {
  int r = blockIdx.y;
  unsigned short* AB2 = ABall + (long)r * MPAD * 128;
  const int* ssrc = ssrc6 + (long)r * EE;
  int l = threadIdx.x & 63;
  int n = blockIdx.x * 4 + (threadIdx.x >> 6);
  if (n >= NN) return;
  float acc = 0.f;
  int st = off6[(long)r * NN + n], cnt = deg6[(long)r * NN + n];
  int i = 0;
  for (; i + 4 <= cnt; i += 4) {
    int s0 = ssrc[st + i], s1 = ssrc[st + i + 1], s2 = ssrc[st + i + 2], s3 = ssrc[st + i + 3];
    acc += b2f(AB2[(long)s0 * 128 + OO + l]) + b2f(AB2[(long)s1 * 128 + OO + l]) +
           b2f(AB2[(long)s2 * 128 + OO + l]) + b2f(AB2[(long)s3 * 128 + OO + l]);
  }
  for (; i < cnt; i++) {
    int s = ssrc[st + i];
    acc += b2f(AB2[(long)s * 128 + OO + l]);
  }
  AB2[(long)n * 128 + l] = f2b(acc);
}

extern "C" void kernel_launch(void* const* d_in, const int* in_sizes, int n_in,
                              void* d_out, int out_size, void* d_ws, size_t ws_size,
                              hipStream_t stream) {
  (void)in_sizes; (void)n_in; (void)out_size;
  const float* x      = (const float*)d_in[0];
  const int*   ei     = (const int*)d_in[1];
  const float* Wl     = (const float*)d_in[2];
  const float* Wr     = (const float*)d_in[3];
  const float* att    = (const float*)d_in[4];
  const float* bg     = (const float*)d_in[5];
  const float* Wrel1  = (const float*)d_in[6];
  const float* Wroot1 = (const float*)d_in[7];
  const float* b1     = (const float*)d_in[8];
  const float* Wrel2  = (const float*)d_in[9];
  const float* Wroot2 = (const float*)d_in[10];
  const float* b2     = (const float*)d_in[11];
  float* out = (float*)d_out;

  char* ws = (char*)d_ws;
  size_t ofs = 0;
  auto alloc = [&](size_t bytes) {
    char* p = ws + ofs;
    ofs += (bytes + 255) & ~(size_t)255;
    return p;
  };
  unsigned short* Xb   = (unsigned short*)alloc((size_t)MPAD * DD * 2);
  unsigned short* Wt   = (unsigned short*)alloc((size_t)RREL * 512 * DD * 2);
  unsigned short* Wt1  = (unsigned short*)alloc((size_t)RREL * 64 * 512 * 2);
  unsigned short* Wt2  = (unsigned short*)alloc((size_t)RREL * 64 * 128 * 2);
  unsigned short* Yall = (unsigned short*)alloc((size_t)RREL * MPAD * 512 * 2);  // 307 MB
  unsigned short* AB2  = (unsigned short*)alloc((size_t)RREL * MPAD * 128 * 2);  // 77 MB
  int* deg6   = (int*)alloc((size_t)RREL * NN * 4);
  int* off6   = (int*)alloc((size_t)RREL * NN * 4);
  int* cur6   = (int*)alloc((size_t)RREL * NN * 4);
  int* bsum   = (int*)alloc((size_t)RREL * SCAN_B * 4);
  int* ssrc6  = (int*)alloc((size_t)RREL * EE * 4);
  if (ofs > ws_size) return;

  k_cvt_x<<<(int)((long)MPAD * DD / 8 / 256), 256, 0, stream>>>(x, Xb);
  k_repack_w<<<dim3(DD / 32, 512 / 32, RREL), 256, 0, stream>>>(Wl, Wr, Wt);
  k_repack_gc<<<(RREL * 64 * 512 + 255) / 256, 256, 0, stream>>>(Wrel1, Wroot1, Wt1, 512);
  k_repack_gc<<<(RREL * 64 * 128 + 255) / 256, 256, 0, stream>>>(Wrel2, Wroot2, Wt2, 128);
  hipMemsetAsync(deg6, 0, (size_t)RREL * NN * 4, stream);
  k_deg6<<<((long)RREL * EE + 255) / 256, 256, 0, stream>>>(ei, deg6);
  k_bsum<<<dim3(SCAN_B, RREL), 256, 0, stream>>>(deg6, bsum);
  k_bscan<<<1, 384, 0, stream>>>(bsum);
  k_boff<<<dim3(SCAN_B, RREL), 256, 0, stream>>>(deg6, bsum, off6, cur6);
  k_scatter6<<<((long)RREL * EE + 255) / 256, 256, 0, stream>>>(ei, cur6, ssrc6);

  // one fused GEMM: all relations, all 3072 output columns
  k_gemm<<<dim3(MPAD / 128, 24), 256, 0, stream>>>((const short*)Xb, (const short*)Wt, Yall);
  // batched edge + gc stages (blockIdx.y = relation)
  k_gat<<<dim3(NN / 4, RREL), 256, 0, stream>>>(Yall, ssrc6, off6, deg6, att, bg);
  k_agg1<<<dim3(NN / 4, RREL), 256, 0, stream>>>(Yall, ssrc6, off6, deg6);
  k_gcgemm<512, true, true><<<dim3(MPAD / 128, RREL), 256, 0, stream>>>(
      (const short*)Yall, (const short*)Wt1, b1, (void*)AB2, 128, OO, (long)MPAD * 128);
  k_agg2<<<dim3(NN / 4, RREL), 256, 0, stream>>>(AB2, ssrc6, off6, deg6);
  k_gcgemm<128, false, false><<<dim3(MPAD / 128, RREL), 256, 0, stream>>>(
      (const short*)AB2, (const short*)Wt2, b2, (void*)out, RREL * OO, 0, 64);
}